// Round 7
// baseline (305.620 us; speedup 1.0000x reference)
//
#include <hip/hip_runtime.h>
#include <stdint.h>

// Problem constants
#define ROWS  16384   // B*T = 512*32
#define CELL  128
#define INF   512
#define NSTEP 32

typedef _Float16 f16x8 __attribute__((ext_vector_type(8)));
typedef _Float16 f16x4 __attribute__((ext_vector_type(4)));
typedef float    f32x4 __attribute__((ext_vector_type(4)));

#define MFMA16(a, b, c) __builtin_amdgcn_mfma_f32_16x16x32_f16((a), (b), (c), 0, 0, 0)

// ws layout (f16 elems), all in 16x16x32 fragment order:
//   A_sw[g]  at g*16384          (g=0..3: Wf,Wi1,Wi2,Wo rows 0..127, cell part)
//   Xw_sw[g] at 65536 + g*65536  (rows 128..639, x part)
//   Wc_sw    at 327680
// frag addr: ((ks*8 + nb)*64 + lane)*8 + j  <->
//   W[ks*32 + ((lane>>4)<<3) + j][nb*16 + (lane&15)]
// Weights PRE-SCALED: Wf,Wi1,Wo by log2(e); Wi2 by 2*log2(e); Wc by log2(e).
#define AOFF  0
#define XOFF  65536
#define WCOFF 327680
#define WSTOT 344064

#define LOG2E  1.44269504f
#define LOG2E2 2.88539008f

__device__ __forceinline__ unsigned short f2h_bits(float f) {
  _Float16 h = (_Float16)f;
  return *(unsigned short*)&h;
}
// z pre-scaled by log2e: sigmoid(z_real) = 1/(1+2^(-z))
__device__ __forceinline__ float sig2(float z) {
  return __builtin_amdgcn_rcpf(1.f + __builtin_amdgcn_exp2f(-z));
}
// z pre-scaled by 2*log2e: tanh(z_real) = 1 - 2/(2^z + 1)
__device__ __forceinline__ float tanh2(float z) {
  return 1.f - 2.f * __builtin_amdgcn_rcpf(__builtin_amdgcn_exp2f(z) + 1.f);
}

__global__ __launch_bounds__(256) void prep_kernel(
    const float* __restrict__ Wf, const float* __restrict__ Wi1,
    const float* __restrict__ Wi2, const float* __restrict__ Wo,
    const float* __restrict__ Wc, unsigned short* __restrict__ ws) {
  int id = blockIdx.x * blockDim.x + threadIdx.x;
  if (id >= WSTOT) return;
  const float* Wg[4] = {Wf, Wi1, Wi2, Wo};
  const float scl[4] = {LOG2E, LOG2E, LOG2E2, LOG2E};
  float v;
  int k, n, base;
  if (id < XOFF) {                       // recurrent (cell) part, k = 0..127
    int g = id >> 14, r = id & 16383;
    k = r >> 7; n = r & 127;
    v = Wg[g][k * CELL + n] * scl[g];
    base = g * 16384;
  } else if (id < WCOFF) {               // x part, k = 0..511 -> W row 128+k
    int t = id - XOFF;
    int g = t >> 16, r = t & 65535;
    k = r >> 7; n = r & 127;
    v = Wg[g][(CELL + k) * CELL + n] * scl[g];
    base = XOFF + g * 65536;
  } else {                               // Wc [128][128], scaled by log2e
    int r = id - WCOFF;
    k = r >> 7; n = r & 127;
    v = Wc[k * CELL + n] * LOG2E;
    base = WCOFF;
  }
  int ks = k >> 5, kk = k & 31;
  int lane = ((kk >> 3) << 4) | (n & 15);
  int j = kk & 7, nb = n >> 4;
  ws[base + ((ks * 8 + nb) * 64 + lane) * 8 + j] = f2h_bits(v);
}

// BARRIER-FREE recurrence: one wave owns 16 rows x ALL 128 cols.
//   - Wf, Wi1 weight frags: 256 VGPR (2 gates x 8 col-tiles x 4 ks)
//   - Wi2: block-shared LDS copy, 32 b128 reads/step
//   - u (x@Wx+b): f16 in 48 VGPR (f,i1,i2); u_o f16 in LDS
//   - c: f32 carry in regs; D-layout -> B-frag exchange via a PRIVATE 4KB
//     LDS tile (8 ds_write_b64 + 4 ds_read_b128), same-wave lgkm ordering
//     only => ZERO __syncthreads in the 31-step loop.
// 1024 waves = 1/SIMD (VGPR ~430), grid 256 x 4 waves, 64KB LDS/block.
__global__ __launch_bounds__(256, 1) void lstm_kernel(
    const float* __restrict__ x,
    const float* __restrict__ bf_, const float* __restrict__ bi1,
    const float* __restrict__ bi2, const float* __restrict__ bo,
    const float* __restrict__ bc,
    const unsigned short* __restrict__ ws, float* __restrict__ out) {

  __shared__ _Float16 wi2S[16384];   // 32KB Wi2 cell-part frags (block-shared)
  __shared__ _Float16 uoS[8192];     // 16KB u_o f16 [w][nb][lane][4]
  __shared__ _Float16 cT[8192];      // 16KB per-wave private c tiles (swz)

  const int tid  = threadIdx.x;
  const int lane = tid & 63;
  const int w    = tid >> 6;       // wave 0..3
  const int n16  = lane & 15;      // batch row (C/D layout: batch = lane&15)
  const int g4   = lane >> 4;      // 0..3
  const int sxor = n16 & 7;
  const int myrow = blockIdx.x * 64 + w * 16 + n16;

  const _Float16* Aw  = (const _Float16*)ws + AOFF;
  const _Float16* XwP = (const _Float16*)ws + XOFF;
  const _Float16* Wcw = (const _Float16*)ws + WCOFF;

  // ---- stage Wi2 cell-part (32KB) into LDS (only cross-wave dependency) --
#pragma unroll
  for (int i = 0; i < 8; ++i) {
    int idx = tid + i * 256;
    *(f16x8*)&wi2S[idx * 8] = *(const f16x8*)(Aw + 2 * 16384 + idx * 8);
  }

  // ---------------- prologue: u[g][nb] = x @ Wg[128:,:] -------------------
  f32x4 u[4][8];
#pragma unroll
  for (int g = 0; g < 4; ++g)
#pragma unroll
    for (int nb = 0; nb < 8; ++nb)
#pragma unroll
      for (int i = 0; i < 4; ++i) u[g][nb][i] = 0.f;

  const float* xr = x + (size_t)myrow * INF;
#pragma unroll 1
  for (int ks = 0; ks < 16; ++ks) {
    // B-frag of x: lane holds x[myrow][32ks + 8*g4 + j], j=0..7
    float4 x0 = *(const float4*)(xr + ks * 32 + g4 * 8);
    float4 x1 = *(const float4*)(xr + ks * 32 + g4 * 8 + 4);
    f16x8 xa = {(_Float16)x0.x, (_Float16)x0.y, (_Float16)x0.z, (_Float16)x0.w,
                (_Float16)x1.x, (_Float16)x1.y, (_Float16)x1.z, (_Float16)x1.w};
#pragma unroll
    for (int g = 0; g < 4; ++g)
#pragma unroll
      for (int nb = 0; nb < 8; ++nb)
        u[g][nb] = MFMA16(
            *(const f16x8*)(XwP + g * 65536 + ((ks * 8 + nb) * 64 + lane) * 8),
            xa, u[g][nb]);
  }

  // biases; pack f,i1,i2 preactivations to f16 regs; u_o -> LDS f16
  f16x4 u3[3][8];
#pragma unroll
  for (int nb = 0; nb < 8; ++nb) {
    const int c0 = nb * 16 + g4 * 4;
    f32x4 b0 = *(const f32x4*)&bf_[c0];
    f32x4 b1 = *(const f32x4*)&bi1[c0];
    f32x4 b2 = *(const f32x4*)&bi2[c0];
    f32x4 b3 = *(const f32x4*)&bo[c0];
    f16x4 h0, h1, h2, h3;
#pragma unroll
    for (int i = 0; i < 4; ++i) {
      h0[i] = (_Float16)fmaf(b0[i], LOG2E,  u[0][nb][i]);
      h1[i] = (_Float16)fmaf(b1[i], LOG2E,  u[1][nb][i]);
      h2[i] = (_Float16)fmaf(b2[i], LOG2E2, u[2][nb][i]);
      h3[i] = (_Float16)fmaf(b3[i], LOG2E,  u[3][nb][i]);
    }
    u3[0][nb] = h0; u3[1][nb] = h1; u3[2][nb] = h2;
    *(f16x4*)&uoS[w * 2048 + nb * 256 + lane * 4] = h3;
  }
  __syncthreads();   // wi2S staged; the LAST barrier in the kernel

  // ---- recurrent weights for f, i1 gates -> 256 VGPRs --------------------
  f16x8 wrf[8][4], wri[8][4];   // [col-tile nb][ks]
#pragma unroll
  for (int nb = 0; nb < 8; ++nb)
#pragma unroll
    for (int ks = 0; ks < 4; ++ks) {
      wrf[nb][ks] = *(const f16x8*)(Aw + ((ks * 8 + nb) * 64 + lane) * 8);
      wri[nb][ks] = *(const f16x8*)(Aw + 16384 + ((ks * 8 + nb) * 64 + lane) * 8);
    }

  // ---- intra-wave exchange addressing (private 4KB tile, XOR-swz chunks) -
  // store col C of row n16 at: cb + ((C>>3)^sxor)*8 + (C&7)
  const int cb = w * 2048 + n16 * 128;
  const int aoff0 = cb + (((0  + g4) ^ sxor) << 3);
  const int aoff1 = cb + (((4  + g4) ^ sxor) << 3);
  const int aoff2 = cb + (((8  + g4) ^ sxor) << 3);
  const int aoff3 = cb + (((12 + g4) ^ sxor) << 3);
  const int shr   = sxor >> 1;
  const int wbase = cb + (g4 & 1) * 4 + (((g4 >> 1) ^ (sxor & 1)) << 3);
  // write addr for col-tile nb: wbase + ((nb ^ shr) << 4)

  f32x4 cr[8];           // f32 c carry (lane's 32 elements)
  f16x8 a0, a1, a2, a3;  // c B-frags for the wave's 16 rows

  // ---------------- step 0: c_prev = 0 => c = sig(u_i1)*tanh(u_i2) --------
#pragma unroll
  for (int nb = 0; nb < 8; ++nb) {
    f32x4 cn; f16x4 hv;
#pragma unroll
    for (int i = 0; i < 4; ++i) {
      cn[i] = sig2((float)u3[1][nb][i]) * tanh2((float)u3[2][nb][i]);
      hv[i] = (_Float16)cn[i];
    }
    cr[nb] = cn;
    *(f16x4*)&cT[wbase + ((nb ^ shr) << 4)] = hv;
  }
  a0 = *(const f16x8*)&cT[aoff0];
  a1 = *(const f16x8*)&cT[aoff1];
  a2 = *(const f16x8*)&cT[aoff2];
  a3 = *(const f16x8*)&cT[aoff3];

  // ---------------- recurrence: steps 1..30, NO barriers ------------------
#pragma unroll 1
  for (int t = 1; t < NSTEP - 1; ++t) {
#pragma unroll
    for (int nb = 0; nb < 8; ++nb) {
      const f16x8 w0 = *(const f16x8*)&wi2S[((0  + nb) * 64 + lane) * 8];
      const f16x8 w1 = *(const f16x8*)&wi2S[((8  + nb) * 64 + lane) * 8];
      const f16x8 w2 = *(const f16x8*)&wi2S[((16 + nb) * 64 + lane) * 8];
      const f16x8 w3 = *(const f16x8*)&wi2S[((24 + nb) * 64 + lane) * 8];
      f32x4 sf, si, sg;
#pragma unroll
      for (int i = 0; i < 4; ++i) {
        sf[i] = (float)u3[0][nb][i];
        si[i] = (float)u3[1][nb][i];
        sg[i] = (float)u3[2][nb][i];
      }
      f32x4 zf = MFMA16(wrf[nb][0], a0, sf);
      f32x4 zi = MFMA16(wri[nb][0], a0, si);
      f32x4 zg = MFMA16(w0,         a0, sg);
      zf = MFMA16(wrf[nb][1], a1, zf);
      zi = MFMA16(wri[nb][1], a1, zi);
      zg = MFMA16(w1,         a1, zg);
      zf = MFMA16(wrf[nb][2], a2, zf);
      zi = MFMA16(wri[nb][2], a2, zi);
      zg = MFMA16(w2,         a2, zg);
      zf = MFMA16(wrf[nb][3], a3, zf);
      zi = MFMA16(wri[nb][3], a3, zi);
      zg = MFMA16(w3,         a3, zg);
      f32x4 cn; f16x4 hv;
#pragma unroll
      for (int i = 0; i < 4; ++i) {
        float fg = sig2(zf[i]);
        float ig = sig2(zi[i]);
        float gg = tanh2(zg[i]);
        cn[i] = fmaf(cr[nb][i], fg, ig * gg);
        hv[i] = (_Float16)cn[i];
      }
      cr[nb] = cn;
      *(f16x4*)&cT[wbase + ((nb ^ shr) << 4)] = hv;
    }
    // exchange: same-wave lgkm ordering only (compiler inserts waits)
    a0 = *(const f16x8*)&cT[aoff0];
    a1 = *(const f16x8*)&cT[aoff1];
    a2 = *(const f16x8*)&cT[aoff2];
    a3 = *(const f16x8*)&cT[aoff3];
  }

  // ---------------- final step (t=31): + o-gate ---------------------------
#pragma unroll
  for (int nb = 0; nb < 8; ++nb) {
    const f16x8 w0 = *(const f16x8*)&wi2S[((0  + nb) * 64 + lane) * 8];
    const f16x8 w1 = *(const f16x8*)&wi2S[((8  + nb) * 64 + lane) * 8];
    const f16x8 w2 = *(const f16x8*)&wi2S[((16 + nb) * 64 + lane) * 8];
    const f16x8 w3 = *(const f16x8*)&wi2S[((24 + nb) * 64 + lane) * 8];
    const f16x8 o0 = *(const f16x8*)(Aw + 3 * 16384 + ((0  + nb) * 64 + lane) * 8);
    const f16x8 o1 = *(const f16x8*)(Aw + 3 * 16384 + ((8  + nb) * 64 + lane) * 8);
    const f16x8 o2 = *(const f16x8*)(Aw + 3 * 16384 + ((16 + nb) * 64 + lane) * 8);
    const f16x8 o3 = *(const f16x8*)(Aw + 3 * 16384 + ((24 + nb) * 64 + lane) * 8);
    f16x4 uoh = *(const f16x4*)&uoS[w * 2048 + nb * 256 + lane * 4];
    f32x4 sf, si, sg, so;
#pragma unroll
    for (int i = 0; i < 4; ++i) {
      sf[i] = (float)u3[0][nb][i];
      si[i] = (float)u3[1][nb][i];
      sg[i] = (float)u3[2][nb][i];
      so[i] = (float)uoh[i];
    }
    f32x4 zf = MFMA16(wrf[nb][0], a0, sf);
    f32x4 zi = MFMA16(wri[nb][0], a0, si);
    f32x4 zg = MFMA16(w0,         a0, sg);
    f32x4 zo = MFMA16(o0,         a0, so);
    zf = MFMA16(wrf[nb][1], a1, zf);
    zi = MFMA16(wri[nb][1], a1, zi);
    zg = MFMA16(w1,         a1, zg);
    zo = MFMA16(o1,         a1, zo);
    zf = MFMA16(wrf[nb][2], a2, zf);
    zi = MFMA16(wri[nb][2], a2, zi);
    zg = MFMA16(w2,         a2, zg);
    zo = MFMA16(o2,         a2, zo);
    zf = MFMA16(wrf[nb][3], a3, zf);
    zi = MFMA16(wri[nb][3], a3, zi);
    zg = MFMA16(w3,         a3, zg);
    zo = MFMA16(o3,         a3, zo);
    f32x4 cn; f16x4 hv;
#pragma unroll
    for (int i = 0; i < 4; ++i) {
      float fg = sig2(zf[i]);
      float ig = sig2(zi[i]);
      float gg = tanh2(zg[i]);
      cn[i] = fmaf(cr[nb][i], fg, ig * gg);
      float ov = sig2(zo[i]) * tanh2(cn[i] * LOG2E2);  // cn unscaled
      hv[i] = (_Float16)ov;
    }
    cr[nb] = cn;   // final c
    // a0..a3 already hold c(t=30) in regs: safe to overwrite cT with o
    *(f16x4*)&cT[wbase + ((nb ^ shr) << 4)] = hv;
  }
  // o B-frags via the same private exchange
  a0 = *(const f16x8*)&cT[aoff0];
  a1 = *(const f16x8*)&cT[aoff1];
  a2 = *(const f16x8*)&cT[aoff2];
  a3 = *(const f16x8*)&cT[aoff3];

  // -------- epilogue: e = exp2(o @ Wc_scaled + bc*log2e), softmax ---------
  // |s| small (o in (-1,1), Wc ~ N(0,1/sqrt(128))) => max-free softmax.
  f32x4 ev[8];
#pragma unroll
  for (int nb = 0; nb < 8; ++nb) {
    f32x4 sa = {0.f, 0.f, 0.f, 0.f};
    sa = MFMA16(*(const f16x8*)(Wcw + ((0  + nb) * 64 + lane) * 8), a0, sa);
    sa = MFMA16(*(const f16x8*)(Wcw + ((8  + nb) * 64 + lane) * 8), a1, sa);
    sa = MFMA16(*(const f16x8*)(Wcw + ((16 + nb) * 64 + lane) * 8), a2, sa);
    sa = MFMA16(*(const f16x8*)(Wcw + ((24 + nb) * 64 + lane) * 8), a3, sa);
    f32x4 bcv = *(const f32x4*)&bc[nb * 16 + g4 * 4];
#pragma unroll
    for (int i = 0; i < 4; ++i)
      ev[nb][i] = __builtin_amdgcn_exp2f(fmaf(bcv[i], LOG2E, sa[i]));
  }
  float sm = 0.f;
#pragma unroll
  for (int nb = 0; nb < 8; ++nb)
#pragma unroll
    for (int i = 0; i < 4; ++i) sm += ev[nb][i];
  // row n16's 128 cols live in lanes {n16, n16+16, n16+32, n16+48}
  sm += __shfl_xor(sm, 16, 64);
  sm += __shfl_xor(sm, 32, 64);
  float inv = __builtin_amdgcn_rcpf(sm);

  float* orow = out + (size_t)myrow * 128 + g4 * 4;
#pragma unroll
  for (int nb = 0; nb < 8; ++nb) {
    f32x4 o4;
#pragma unroll
    for (int i = 0; i < 4; ++i) o4[i] = ev[nb][i] * inv;
    *(f32x4*)&orow[nb * 16] = o4;
  }
  float* crow = out + (size_t)ROWS * 128 + (size_t)myrow * 128 + g4 * 4;
#pragma unroll
  for (int nb = 0; nb < 8; ++nb)
    *(f32x4*)&crow[nb * 16] = cr[nb];
}

extern "C" void kernel_launch(void* const* d_in, const int* in_sizes, int n_in,
                              void* d_out, int out_size, void* d_ws, size_t ws_size,
                              hipStream_t stream) {
  const float* x   = (const float*)d_in[0];
  const float* Wf  = (const float*)d_in[1];
  const float* bf_ = (const float*)d_in[2];
  const float* Wi1 = (const float*)d_in[3];
  const float* bi1 = (const float*)d_in[4];
  const float* Wi2 = (const float*)d_in[5];
  const float* bi2 = (const float*)d_in[6];
  const float* Wo  = (const float*)d_in[7];
  const float* bo  = (const float*)d_in[8];
  const float* Wc  = (const float*)d_in[9];
  const float* bc  = (const float*)d_in[10];
  unsigned short* ws = (unsigned short*)d_ws;
  float* out = (float*)d_out;

  hipLaunchKernelGGL(prep_kernel, dim3((WSTOT + 255) / 256), dim3(256), 0, stream,
                     Wf, Wi1, Wi2, Wo, Wc, ws);
  hipLaunchKernelGGL(lstm_kernel, dim3(ROWS / 64), dim3(256), 0, stream,
                     x, bf_, bi1, bi2, bo, bc, ws, out);
}

// Round 8
// 237.084 us; speedup vs baseline: 1.2891x; 1.2891x over previous
//
#include <hip/hip_runtime.h>
#include <stdint.h>

// Problem constants
#define ROWS  16384   // B*T = 512*32
#define CELL  128
#define INF   512
#define NSTEP 32

typedef _Float16 f16x8 __attribute__((ext_vector_type(8)));
typedef _Float16 f16x4 __attribute__((ext_vector_type(4)));
typedef float    f32x4 __attribute__((ext_vector_type(4)));
typedef unsigned int u32x4 __attribute__((ext_vector_type(4)));

#define MFMA16(a, b, c) __builtin_amdgcn_mfma_f32_16x16x32_f16((a), (b), (c), 0, 0, 0)

// ws layout (f16 elems), all in 16x16x32 fragment order:
//   A_sw[g]  at g*16384          (g=0..3: Wf,Wi1,Wi2,Wo rows 0..127, cell part)
//   Xw_sw[g] at 65536 + g*65536  (rows 128..639, x part)
//   Wc_sw    at 327680
// frag addr: ((ks*8 + nb)*64 + lane)*8 + j  <->
//   W[ks*32 + ((lane>>4)<<3) + j][nb*16 + (lane&15)]
// Weights PRE-SCALED: Wf,Wi1,Wo by log2(e); Wi2 by 2*log2(e); Wc by log2(e).
#define AOFF  0
#define XOFF  65536
#define WCOFF 327680
#define WSTOT 344064

#define LOG2E  1.44269504f
#define LOG2E2 2.88539008f

__device__ __forceinline__ unsigned short f2h_bits(float f) {
  _Float16 h = (_Float16)f;
  return *(unsigned short*)&h;
}
__device__ __forceinline__ float f16lo(unsigned v) {
  unsigned short b = (unsigned short)(v & 0xffffu);
  _Float16 h; __builtin_memcpy(&h, &b, 2); return (float)h;
}
__device__ __forceinline__ float f16hi(unsigned v) {
  unsigned short b = (unsigned short)(v >> 16);
  _Float16 h; __builtin_memcpy(&h, &b, 2); return (float)h;
}
// z pre-scaled by log2e: sigmoid(z_real) = 1/(1+2^(-z))
__device__ __forceinline__ float sig2(float z) {
  return __builtin_amdgcn_rcpf(1.f + __builtin_amdgcn_exp2f(-z));
}
// z pre-scaled by 2*log2e: tanh(z_real) = 1 - 2/(2^z + 1)
__device__ __forceinline__ float tanh2(float z) {
  return 1.f - 2.f * __builtin_amdgcn_rcpf(__builtin_amdgcn_exp2f(z) + 1.f);
}

__global__ __launch_bounds__(256) void prep_kernel(
    const float* __restrict__ Wf, const float* __restrict__ Wi1,
    const float* __restrict__ Wi2, const float* __restrict__ Wo,
    const float* __restrict__ Wc, unsigned short* __restrict__ ws) {
  int id = blockIdx.x * blockDim.x + threadIdx.x;
  if (id >= WSTOT) return;
  const float* Wg[4] = {Wf, Wi1, Wi2, Wo};
  const float scl[4] = {LOG2E, LOG2E, LOG2E2, LOG2E};
  float v;
  int k, n, base;
  if (id < XOFF) {                       // recurrent (cell) part, k = 0..127
    int g = id >> 14, r = id & 16383;
    k = r >> 7; n = r & 127;
    v = Wg[g][k * CELL + n] * scl[g];
    base = g * 16384;
  } else if (id < WCOFF) {               // x part, k = 0..511 -> W row 128+k
    int t = id - XOFF;
    int g = t >> 16, r = t & 65535;
    k = r >> 7; n = r & 127;
    v = Wg[g][(CELL + k) * CELL + n] * scl[g];
    base = XOFF + g * 65536;
  } else {                               // Wc [128][128], scaled by log2e
    int r = id - WCOFF;
    k = r >> 7; n = r & 127;
    v = Wc[k * CELL + n] * LOG2E;
    base = WCOFF;
  }
  int ks = k >> 5, kk = k & 31;
  int lane = ((kk >> 3) << 4) | (n & 15);
  int j = kk & 7, nb = n >> 4;
  ws[base + ((ks * 8 + nb) * 64 + lane) * 8 + j] = f2h_bits(v);
}

// BARRIER-FREE recurrence, register-disciplined (R7 redo):
// one wave = 16 rows x 128 cols; persistent regs ~190 (f-weights 128 +
// cr 32 + a-frags 16). Streamed per step: i2 weights from LDS (32KB),
// i1 weights from global (32KB hot -> L1), u_i1 from LDS, u_f+u_i2
// f16-packed in OUT-buffer scratch (own rows; overwritten after last
// read), u_o in the final-c out region. LDS = 32+16+16 = 64KB exact.
// LICM of invariant stream loads defeated by asm-laundered zero offset.
// Zero __syncthreads in the 31-step loop.
__global__ __launch_bounds__(256, 1) void lstm_kernel(
    const float* __restrict__ x,
    const float* __restrict__ bf_, const float* __restrict__ bi1,
    const float* __restrict__ bi2, const float* __restrict__ bo,
    const float* __restrict__ bc,
    const unsigned short* __restrict__ ws, float* __restrict__ out) {

  __shared__ union {
    _Float16 xw[32768];                // 64KB: prologue Xw chunk staging
    struct {
      _Float16 wi2[16384];             // 32KB Wi2 cell-part frags
      _Float16 cT[8192];               // 16KB per-wave c exchange tiles (swz)
      _Float16 ui1[8192];              // 16KB u_i1 seeds f16
    } r;
  } S;

  const int tid  = threadIdx.x;
  const int lane = tid & 63;
  const int w    = tid >> 6;       // wave 0..3
  const int n16  = lane & 15;      // batch row (C/D layout: batch = lane&15)
  const int g4   = lane >> 4;      // 0..3
  const int sxor = n16 & 7;
  const int myrow = blockIdx.x * 64 + w * 16 + n16;
  const int fB   = (blockIdx.x * 32 + w * 8) * 64 + lane;  // scratch flat base

  const _Float16* Aw  = (const _Float16*)ws + AOFF;
  const _Float16* XwP = (const _Float16*)ws + XOFF;
  const _Float16* Wcw = (const _Float16*)ws + WCOFF;
  unsigned* outU = (unsigned*)out;                    // u_f|u_i2 packed scratch
  float*    uoG  = out + (size_t)ROWS * 128;          // u_o scratch (f32)

  // ---------------- prologue: u[g][nb] = x @ Wg[128:,:] -------------------
  // Xw staged through LDS in 8 chunks (2 ks each) -> 512KB L2 per block once.
  f32x4 u[4][8];
#pragma unroll
  for (int g = 0; g < 4; ++g)
#pragma unroll
    for (int nb = 0; nb < 8; ++nb)
#pragma unroll
      for (int i = 0; i < 4; ++i) u[g][nb][i] = 0.f;

  const float* xr = x + (size_t)myrow * INF;
#pragma unroll 1
  for (int ch = 0; ch < 8; ++ch) {
    if (ch) __syncthreads();           // prior chunk's reads done
#pragma unroll
    for (int i = 0; i < 16; ++i) {     // 4096 x f16x8 = 64KB
      int idx = tid + i * 256;
      *(f16x8*)&S.xw[idx * 8] =
          *(const f16x8*)(XwP + (idx >> 10) * 65536 + ch * 8192 + (idx & 1023) * 8);
    }
    __syncthreads();
#pragma unroll
    for (int k2 = 0; k2 < 2; ++k2) {
      int ks = ch * 2 + k2;
      float4 x0 = *(const float4*)(xr + ks * 32 + g4 * 8);
      float4 x1 = *(const float4*)(xr + ks * 32 + g4 * 8 + 4);
      f16x8 xa = {(_Float16)x0.x, (_Float16)x0.y, (_Float16)x0.z, (_Float16)x0.w,
                  (_Float16)x1.x, (_Float16)x1.y, (_Float16)x1.z, (_Float16)x1.w};
#pragma unroll
      for (int g = 0; g < 4; ++g)
#pragma unroll
        for (int nb = 0; nb < 8; ++nb)
          u[g][nb] = MFMA16(
              *(const f16x8*)&S.xw[g * 8192 + ((k2 * 8 + nb) * 64 + lane) * 8],
              xa, u[g][nb]);
    }
  }
  __syncthreads();   // xw reads done; r.* region becomes live

  // ---- stage Wi2 cell-part frags into LDS --------------------------------
#pragma unroll
  for (int i = 0; i < 8; ++i) {
    int idx = tid + i * 256;           // 2048 x f16x8 = 32KB
    *(f16x8*)&S.r.wi2[idx * 8] = *(const f16x8*)(Aw + 2 * 16384 + idx * 8);
  }

  // ---- exchange addressing (private 4KB tile per wave, XOR-swz chunks) ---
  const int cb = w * 2048 + n16 * 128;
  const int aoff0 = cb + (((0  + g4) ^ sxor) << 3);
  const int aoff1 = cb + (((4  + g4) ^ sxor) << 3);
  const int aoff2 = cb + (((8  + g4) ^ sxor) << 3);
  const int aoff3 = cb + (((12 + g4) ^ sxor) << 3);
  const int shr   = sxor >> 1;
  const int wbase = cb + (g4 & 1) * 4 + (((g4 >> 1) ^ (sxor & 1)) << 3);

  // ---- biases + seed distribution + step 0 -------------------------------
  f32x4 cr[8];
#pragma unroll
  for (int nb = 0; nb < 8; ++nb) {
    const int c0i = nb * 16 + g4 * 4;
    f32x4 b0 = *(const f32x4*)&bf_[c0i];
    f32x4 b1 = *(const f32x4*)&bi1[c0i];
    f32x4 b2 = *(const f32x4*)&bi2[c0i];
    f32x4 b3 = *(const f32x4*)&bo[c0i];
    u32x4 pk;
    f16x4 hi1, hv;
    f32x4 zov;
#pragma unroll
    for (int i = 0; i < 4; ++i) {
      float zf_  = fmaf(b0[i], LOG2E,  u[0][nb][i]);
      float zi1_ = fmaf(b1[i], LOG2E,  u[1][nb][i]);
      float zi2_ = fmaf(b2[i], LOG2E2, u[2][nb][i]);
      float zo_  = fmaf(b3[i], LOG2E,  u[3][nb][i]);
      pk[i]  = (unsigned)f2h_bits(zf_) | ((unsigned)f2h_bits(zi2_) << 16);
      hi1[i] = (_Float16)zi1_;
      zov[i] = zo_;
      float c0 = sig2(zi1_) * tanh2(zi2_);
      cr[nb][i] = c0;
      hv[i] = (_Float16)c0;
    }
    *(f16x4*)&S.r.ui1[w * 2048 + nb * 256 + lane * 4] = hi1;
    *(u32x4*)&outU[(size_t)(fB + nb * 64) * 4] = pk;
    *(f32x4*)&uoG[(size_t)(fB + nb * 64) * 4] = zov;
    *(f16x4*)&S.r.cT[wbase + ((nb ^ shr) << 4)] = hv;
  }

  // ---- persistent f-gate weights -> 128 VGPRs ----------------------------
  f16x8 wrf[8][4];
#pragma unroll
  for (int nb = 0; nb < 8; ++nb)
#pragma unroll
    for (int ks = 0; ks < 4; ++ks)
      wrf[nb][ks] = *(const f16x8*)(Aw + ((ks * 8 + nb) * 64 + lane) * 8);

  __syncthreads();   // wi2 staged; the LAST barrier in the kernel

  f16x8 a0 = *(const f16x8*)&S.r.cT[aoff0];
  f16x8 a1 = *(const f16x8*)&S.r.cT[aoff1];
  f16x8 a2 = *(const f16x8*)&S.r.cT[aoff2];
  f16x8 a3 = *(const f16x8*)&S.r.cT[aoff3];

  // ---------------- recurrence: steps 1..30, NO barriers ------------------
  unsigned zoff = 0;
#pragma unroll 1
  for (int t = 1; t < NSTEP - 1; ++t) {
    asm volatile("" : "+v"(zoff));     // opaque 0: defeats LICM of stream loads
    const int lz = lane + (int)zoff;
#pragma unroll
    for (int nb = 0; nb < 8; ++nb) {
      // i1 weights (global, L1-hot) + i2 weights (LDS) + seeds
      f16x8 p0 = *(const f16x8*)(Aw + 16384 + ((0  + nb) * 64 + lz) * 8);
      f16x8 p1 = *(const f16x8*)(Aw + 16384 + ((8  + nb) * 64 + lz) * 8);
      f16x8 p2 = *(const f16x8*)(Aw + 16384 + ((16 + nb) * 64 + lz) * 8);
      f16x8 p3 = *(const f16x8*)(Aw + 16384 + ((24 + nb) * 64 + lz) * 8);
      f16x8 q0 = *(const f16x8*)&S.r.wi2[((0  + nb) * 64 + lz) * 8];
      f16x8 q1 = *(const f16x8*)&S.r.wi2[((8  + nb) * 64 + lz) * 8];
      f16x8 q2 = *(const f16x8*)&S.r.wi2[((16 + nb) * 64 + lz) * 8];
      f16x8 q3 = *(const f16x8*)&S.r.wi2[((24 + nb) * 64 + lz) * 8];
      f16x4 sih = *(const f16x4*)&S.r.ui1[w * 2048 + nb * 256 + lz * 4];
      u32x4 pk = *(const u32x4*)&outU[(size_t)(fB + nb * 64 + (int)zoff) * 4];
      f32x4 sf, si, sg;
#pragma unroll
      for (int i = 0; i < 4; ++i) {
        sf[i] = f16lo(pk[i]);
        sg[i] = f16hi(pk[i]);
        si[i] = (float)sih[i];
      }
      f32x4 zf = MFMA16(wrf[nb][0], a0, sf);
      f32x4 zi = MFMA16(p0,         a0, si);
      f32x4 zg = MFMA16(q0,         a0, sg);
      zf = MFMA16(wrf[nb][1], a1, zf);
      zi = MFMA16(p1,         a1, zi);
      zg = MFMA16(q1,         a1, zg);
      zf = MFMA16(wrf[nb][2], a2, zf);
      zi = MFMA16(p2,         a2, zi);
      zg = MFMA16(q2,         a2, zg);
      zf = MFMA16(wrf[nb][3], a3, zf);
      zi = MFMA16(p3,         a3, zi);
      zg = MFMA16(q3,         a3, zg);
      f16x4 hv;
#pragma unroll
      for (int i = 0; i < 4; ++i) {
        float fg = sig2(zf[i]);
        float ig = sig2(zi[i]);
        float gg = tanh2(zg[i]);
        float cn = fmaf(cr[nb][i], fg, ig * gg);
        cr[nb][i] = cn;
        hv[i] = (_Float16)cn;
      }
      *(f16x4*)&S.r.cT[wbase + ((nb ^ shr) << 4)] = hv;
    }
    // intra-wave exchange: lgkm ordering only, no barrier
    a0 = *(const f16x8*)&S.r.cT[aoff0];
    a1 = *(const f16x8*)&S.r.cT[aoff1];
    a2 = *(const f16x8*)&S.r.cT[aoff2];
    a3 = *(const f16x8*)&S.r.cT[aoff3];
  }

  // ---------------- final step (t=31): + o-gate ---------------------------
#pragma unroll
  for (int nb = 0; nb < 8; ++nb) {
    f16x8 p0 = *(const f16x8*)(Aw + 16384 + ((0  + nb) * 64 + lane) * 8);
    f16x8 p1 = *(const f16x8*)(Aw + 16384 + ((8  + nb) * 64 + lane) * 8);
    f16x8 p2 = *(const f16x8*)(Aw + 16384 + ((16 + nb) * 64 + lane) * 8);
    f16x8 p3 = *(const f16x8*)(Aw + 16384 + ((24 + nb) * 64 + lane) * 8);
    f16x8 q0 = *(const f16x8*)&S.r.wi2[((0  + nb) * 64 + lane) * 8];
    f16x8 q1 = *(const f16x8*)&S.r.wi2[((8  + nb) * 64 + lane) * 8];
    f16x8 q2 = *(const f16x8*)&S.r.wi2[((16 + nb) * 64 + lane) * 8];
    f16x8 q3 = *(const f16x8*)&S.r.wi2[((24 + nb) * 64 + lane) * 8];
    f16x8 o0 = *(const f16x8*)(Aw + 3 * 16384 + ((0  + nb) * 64 + lane) * 8);
    f16x8 o1 = *(const f16x8*)(Aw + 3 * 16384 + ((8  + nb) * 64 + lane) * 8);
    f16x8 o2 = *(const f16x8*)(Aw + 3 * 16384 + ((16 + nb) * 64 + lane) * 8);
    f16x8 o3 = *(const f16x8*)(Aw + 3 * 16384 + ((24 + nb) * 64 + lane) * 8);
    f16x4 sih = *(const f16x4*)&S.r.ui1[w * 2048 + nb * 256 + lane * 4];
    u32x4 pk = *(const u32x4*)&outU[(size_t)(fB + nb * 64) * 4];
    f32x4 so = *(const f32x4*)&uoG[(size_t)(fB + nb * 64) * 4];
    f32x4 sf, si, sg;
#pragma unroll
    for (int i = 0; i < 4; ++i) {
      sf[i] = f16lo(pk[i]);
      sg[i] = f16hi(pk[i]);
      si[i] = (float)sih[i];
    }
    f32x4 zf = MFMA16(wrf[nb][0], a0, sf);
    f32x4 zi = MFMA16(p0,         a0, si);
    f32x4 zg = MFMA16(q0,         a0, sg);
    f32x4 zo = MFMA16(o0,         a0, so);
    zf = MFMA16(wrf[nb][1], a1, zf);
    zi = MFMA16(p1,         a1, zi);
    zg = MFMA16(q1,         a1, zg);
    zo = MFMA16(o1,         a1, zo);
    zf = MFMA16(wrf[nb][2], a2, zf);
    zi = MFMA16(p2,         a2, zi);
    zg = MFMA16(q2,         a2, zg);
    zo = MFMA16(o2,         a2, zo);
    zf = MFMA16(wrf[nb][3], a3, zf);
    zi = MFMA16(p3,         a3, zi);
    zg = MFMA16(q3,         a3, zg);
    zo = MFMA16(o3,         a3, zo);
    f16x4 hv;
#pragma unroll
    for (int i = 0; i < 4; ++i) {
      float fg = sig2(zf[i]);
      float ig = sig2(zi[i]);
      float gg = tanh2(zg[i]);
      float cn = fmaf(cr[nb][i], fg, ig * gg);
      cr[nb][i] = cn;                           // final c
      float ov = sig2(zo[i]) * tanh2(cn * LOG2E2);  // cn unscaled
      hv[i] = (_Float16)ov;
    }
    // a0..a3 hold c(t=30) in regs: safe to overwrite cT with o
    *(f16x4*)&S.r.cT[wbase + ((nb ^ shr) << 4)] = hv;
  }
  // o B-frags via the same private exchange
  a0 = *(const f16x8*)&S.r.cT[aoff0];
  a1 = *(const f16x8*)&S.r.cT[aoff1];
  a2 = *(const f16x8*)&S.r.cT[aoff2];
  a3 = *(const f16x8*)&S.r.cT[aoff3];

  // -------- epilogue: e = exp2(o @ Wc_scaled + bc*log2e), softmax ---------
  // |s| small (o in (-1,1), Wc ~ N(0,1/sqrt(128))) => max-free softmax.
  f32x4 ev[8];
#pragma unroll
  for (int nb = 0; nb < 8; ++nb) {
    f32x4 sa = {0.f, 0.f, 0.f, 0.f};
    sa = MFMA16(*(const f16x8*)(Wcw + ((0  + nb) * 64 + lane) * 8), a0, sa);
    sa = MFMA16(*(const f16x8*)(Wcw + ((8  + nb) * 64 + lane) * 8), a1, sa);
    sa = MFMA16(*(const f16x8*)(Wcw + ((16 + nb) * 64 + lane) * 8), a2, sa);
    sa = MFMA16(*(const f16x8*)(Wcw + ((24 + nb) * 64 + lane) * 8), a3, sa);
    f32x4 bcv = *(const f32x4*)&bc[nb * 16 + g4 * 4];
#pragma unroll
    for (int i = 0; i < 4; ++i)
      ev[nb][i] = __builtin_amdgcn_exp2f(fmaf(bcv[i], LOG2E, sa[i]));
  }
  float sm = 0.f;
#pragma unroll
  for (int nb = 0; nb < 8; ++nb)
#pragma unroll
    for (int i = 0; i < 4; ++i) sm += ev[nb][i];
  // row n16's 128 cols live in lanes {n16, n16+16, n16+32, n16+48}
  sm += __shfl_xor(sm, 16, 64);
  sm += __shfl_xor(sm, 32, 64);
  float inv = __builtin_amdgcn_rcpf(sm);

  // overwrite scratch regions with the real outputs (all reads done above)
  float* orow = out + (size_t)myrow * 128 + g4 * 4;
#pragma unroll
  for (int nb = 0; nb < 8; ++nb) {
    f32x4 o4;
#pragma unroll
    for (int i = 0; i < 4; ++i) o4[i] = ev[nb][i] * inv;
    *(f32x4*)&orow[nb * 16] = o4;
  }
  float* crow = out + (size_t)ROWS * 128 + (size_t)myrow * 128 + g4 * 4;
#pragma unroll
  for (int nb = 0; nb < 8; ++nb)
    *(f32x4*)&crow[nb * 16] = cr[nb];
}

extern "C" void kernel_launch(void* const* d_in, const int* in_sizes, int n_in,
                              void* d_out, int out_size, void* d_ws, size_t ws_size,
                              hipStream_t stream) {
  const float* x   = (const float*)d_in[0];
  const float* Wf  = (const float*)d_in[1];
  const float* bf_ = (const float*)d_in[2];
  const float* Wi1 = (const float*)d_in[3];
  const float* bi1 = (const float*)d_in[4];
  const float* Wi2 = (const float*)d_in[5];
  const float* bi2 = (const float*)d_in[6];
  const float* Wo  = (const float*)d_in[7];
  const float* bo  = (const float*)d_in[8];
  const float* Wc  = (const float*)d_in[9];
  const float* bc  = (const float*)d_in[10];
  unsigned short* ws = (unsigned short*)d_ws;
  float* out = (float*)d_out;

  hipLaunchKernelGGL(prep_kernel, dim3((WSTOT + 255) / 256), dim3(256), 0, stream,
                     Wf, Wi1, Wi2, Wo, Wc, ws);
  hipLaunchKernelGGL(lstm_kernel, dim3(ROWS / 64), dim3(256), 0, stream,
                     x, bf_, bi1, bi2, bo, bc, ws, out);
}

// Round 9
// 165.152 us; speedup vs baseline: 1.8505x; 1.4355x over previous
//
#include <hip/hip_runtime.h>
#include <stdint.h>

// Problem constants
#define ROWS  16384   // B*T = 512*32
#define CELL  128
#define INF   512
#define RPB   16      // rows per block
#define NSTEP 32

typedef _Float16 f16x8 __attribute__((ext_vector_type(8)));
typedef _Float16 f16x4 __attribute__((ext_vector_type(4)));
typedef float    f32x4 __attribute__((ext_vector_type(4)));

#define MFMA16(a, b, c) __builtin_amdgcn_mfma_f32_16x16x32_f16((a), (b), (c), 0, 0, 0)

// ws layout (f16 elems), all in 16x16x32 fragment order (A and B frag layouts
// are identical on gfx950: element dim = lane&15, k = (lane>>4)*8 + j):
//   A_sw[g]  at g*16384          (g=0..3: Wf,Wi1,Wi2,Wo rows 0..127, cell part)
//   Xw_sw[g] at 65536 + g*65536  (rows 128..639, x part)
//   Wc_sw    at 327680
// frag addr: ((ks*8 + nb)*64 + lane)*8 + j  <->
//   W[ks*32 + ((lane>>4)<<3) + j][nb*16 + (lane&15)]
// Weights PRE-SCALED: Wf,Wi1,Wo by log2(e); Wi2 by 2*log2(e); Wc by log2(e).
#define AOFF  0
#define XOFF  65536
#define WCOFF 327680
#define WSTOT 344064
#define NT8   (WSTOT / 8)   // 43008 threads, one f16x8 store each

#define LOG2E  1.44269504f
#define LOG2E2 2.88539008f

__device__ __forceinline__ float sig2(float z) {
  return __builtin_amdgcn_rcpf(1.f + __builtin_amdgcn_exp2f(-z));
}
__device__ __forceinline__ float tanh2(float z) {
  return 1.f - 2.f * __builtin_amdgcn_rcpf(__builtin_amdgcn_exp2f(z) + 1.f);
}

// prep v2: COALESCED. Thread t emits ws[t*8 .. t*8+7] (one aligned b128
// store; a wave's stores are 1KB contiguous). The 8 f16 are k-consecutive
// elements of one W column (j indexes k in the frag layout), so reads are
// 8 loads at 512B stride, 64B-segment coalesced across lanes.
// Index-equivalent to the verified v1 scatter version.
__global__ __launch_bounds__(256) void prep_kernel(
    const float* __restrict__ Wf, const float* __restrict__ Wi1,
    const float* __restrict__ Wi2, const float* __restrict__ Wo,
    const float* __restrict__ Wc, unsigned short* __restrict__ ws) {
  int t = blockIdx.x * blockDim.x + threadIdx.x;
  if (t >= NT8) return;
  const float* Wg[4] = {Wf, Wi1, Wi2, Wo};
  const float scl[4] = {LOG2E, LOG2E, LOG2E2, LOG2E};
  const int lane = t & 63;
  const int tile = t >> 6;             // global 512-f16 tile, 0..671

  const float* src;
  float sc;
  int ks, nb;
  if (tile < 128) {                    // A region: recurrent (cell) part
    int g = tile >> 5, tA = tile & 31;
    ks = tA >> 3; nb = tA & 7;
    sc = scl[g];
    src = Wg[g];                       // rows 0..127
  } else if (tile < 640) {             // X region: x part, W rows 128..639
    int rel = tile - 128;
    int g = rel >> 7, tX = rel & 127;
    ks = tX >> 3; nb = tX & 7;
    sc = scl[g];
    src = Wg[g] + 128 * CELL;
  } else {                             // Wc region
    int rel = tile - 640;
    ks = rel >> 3; nb = rel & 7;
    sc = LOG2E;
    src = Wc;
  }
  const int k0 = ks * 32 + ((lane >> 4) << 3);
  const int n  = nb * 16 + (lane & 15);
  const float* p = src + (size_t)k0 * CELL + n;
  f16x8 hv;
#pragma unroll
  for (int j = 0; j < 8; ++j) hv[j] = (_Float16)(p[j * CELL] * sc);
  *(f16x8*)&ws[(size_t)t * 8] = hv;
}

// 16 rows/block, 8 waves. Swapped MFMA: z = mfma(W_frag, act_frag),
// C/D mapping: batch = lane&15, col = w*16 + (lane>>4)*4 + reg.
// (R4 structure — best measured: lstm ~89 us.)
__global__ __launch_bounds__(512, 4) void lstm_kernel(
    const float* __restrict__ x,
    const float* __restrict__ bf_, const float* __restrict__ bi1,
    const float* __restrict__ bi2, const float* __restrict__ bo,
    const float* __restrict__ bc,
    const unsigned short* __restrict__ ws, float* __restrict__ out) {

  __shared__ _Float16 cF[2][16 * 128];       // 8192 B, double-buffered c (swz)
  __shared__ union {
    _Float16 xs[16 * 512];                   // 16384 B, x staging (swz)
    struct {
      float    e[16][132];                   // 8448 B, softmax exp values
      _Float16 o[16 * 128];                  // 4096 B, o activations (swz)
    } ep;                                    // 12544 B
  } uS;                                      // total LDS: 24576 B

  const int tid  = threadIdx.x;
  const int lane = tid & 63;
  const int w    = tid >> 6;     // wave 0..7
  const int n16  = lane & 15;    // this lane's batch row (output mapping)
  const int g4   = lane >> 4;    // 0..3
  const int sxor = n16 & 7;      // per-row swizzle key
  const int col0 = w * 16 + g4 * 4;  // first of this lane's 4 output columns
  const int r0   = blockIdx.x * RPB;

  const _Float16* Aw  = (const _Float16*)ws + AOFF;
  const _Float16* Xw  = (const _Float16*)ws + XOFF;
  const _Float16* Wcw = (const _Float16*)ws + WCOFF;

  // loop-invariant swizzled fragment offsets (f16 units) for cF / ep.o
  int aoff[4];
#pragma unroll
  for (int ks = 0; ks < 4; ++ks)
    aoff[ks] = n16 * 128 + (((4 * ks + g4) ^ sxor) << 3);
  const int woff = n16 * 128 + (((2 * w + (g4 >> 1)) ^ sxor) << 3) + (g4 & 1) * 4;

  // ---------------- stage x (16 rows x 512 f32 -> f16, swizzled) ----------
  {
    const float* xb = x + (size_t)r0 * INF;
#pragma unroll
    for (int i = 0; i < 4; ++i) {
      int flat = tid + i * 512;            // 2048 = 16 rows * 128 float4
      int row = flat >> 7, c4 = flat & 127;
      const float4 v = ((const float4*)(xb + (size_t)row * INF))[c4];
      f16x4 h = {(_Float16)v.x, (_Float16)v.y, (_Float16)v.z, (_Float16)v.w};
      int idx = row * 512 + (((c4 >> 1) ^ (row & 7)) << 3) + (c4 & 1) * 4;
      *(f16x4*)&uS.xs[idx] = h;
    }
  }
  __syncthreads();

  // ---------------- u_g = x @ Wg[128:,:] + b ------------------------------
  f32x4 u[4];
#pragma unroll
  for (int g = 0; g < 4; ++g)
#pragma unroll
    for (int i = 0; i < 4; ++i) u[g][i] = 0.f;

#pragma unroll 4
  for (int ks = 0; ks < 16; ++ks) {
    f16x8 a = *(const f16x8*)&uS.xs[n16 * 512 + (((4 * ks + g4) ^ sxor) << 3)];
#pragma unroll
    for (int g = 0; g < 4; ++g) {
      f16x8 b = *(const f16x8*)(Xw + g * 65536 + ((ks * 8 + w) * 64 + lane) * 8);
      u[g] = MFMA16(b, a, u[g]);
    }
  }
  {
    f32x4 b0 = *(const f32x4*)&bf_[col0];
    f32x4 b1 = *(const f32x4*)&bi1[col0];
    f32x4 b2 = *(const f32x4*)&bi2[col0];
    f32x4 b3 = *(const f32x4*)&bo[col0];
#pragma unroll
    for (int i = 0; i < 4; ++i) {
      u[0][i] = fmaf(b0[i], LOG2E,  u[0][i]);
      u[1][i] = fmaf(b1[i], LOG2E,  u[1][i]);
      u[2][i] = fmaf(b2[i], LOG2E2, u[2][i]);
      u[3][i] = fmaf(b3[i], LOG2E,  u[3][i]);
    }
  }

  // ---------------- recurrent-gate weights -> registers -------------------
  f16x8 wr[3][4];   // [gate f,i1,i2][ks] -> 48 VGPRs
#pragma unroll
  for (int g = 0; g < 3; ++g)
#pragma unroll
    for (int ks = 0; ks < 4; ++ks)
      wr[g][ks] = *(const f16x8*)(Aw + g * 16384 + ((ks * 8 + w) * 64 + lane) * 8);

  // ---------------- step 0: c_prev = 0 => z = u ---------------------------
  f32x4 cr;
  {
    f16x4 hv;
#pragma unroll
    for (int i = 0; i < 4; ++i) {
      float c0 = sig2(u[1][i]) * tanh2(u[2][i]);
      cr[i] = c0;
      hv[i] = (_Float16)c0;
    }
    *(f16x4*)&cF[0][woff] = hv;            // single b64 store, swizzled
  }
  __syncthreads();

  // ---------------- recurrence: steps 1..30 -------------------------------
#pragma unroll 1
  for (int t = 1; t < NSTEP - 1; ++t) {
    const _Float16* rd = cF[(t + 1) & 1];
    f16x8 a0 = *(const f16x8*)(rd + aoff[0]);
    f16x8 a1 = *(const f16x8*)(rd + aoff[1]);
    f16x8 a2 = *(const f16x8*)(rd + aoff[2]);
    f16x8 a3 = *(const f16x8*)(rd + aoff[3]);
    // seed accumulators from u via the MFMA C operand (no reg copies)
    f32x4 zf  = MFMA16(wr[0][0], a0, u[0]);
    f32x4 zi1 = MFMA16(wr[1][0], a0, u[1]);
    f32x4 zi2 = MFMA16(wr[2][0], a0, u[2]);
    zf  = MFMA16(wr[0][1], a1, zf);
    zi1 = MFMA16(wr[1][1], a1, zi1);
    zi2 = MFMA16(wr[2][1], a1, zi2);
    zf  = MFMA16(wr[0][2], a2, zf);
    zi1 = MFMA16(wr[1][2], a2, zi1);
    zi2 = MFMA16(wr[2][2], a2, zi2);
    zf  = MFMA16(wr[0][3], a3, zf);
    zi1 = MFMA16(wr[1][3], a3, zi1);
    zi2 = MFMA16(wr[2][3], a3, zi2);
    f16x4 hv;
#pragma unroll
    for (int i = 0; i < 4; ++i) {
      float fg = sig2(zf[i]);
      float ig = sig2(zi1[i]);
      float gg = tanh2(zi2[i]);
      float cn = fmaf(cr[i], fg, ig * gg);
      cr[i] = cn;
      hv[i] = (_Float16)cn;
    }
    *(f16x4*)&cF[t & 1][woff] = hv;        // single b64 store, swizzled
    __syncthreads();
  }

  // ---------------- final step (t=31): + o-gate ---------------------------
  {
    const _Float16* rd = cF[0];            // written at t=30
    f16x8 a0 = *(const f16x8*)(rd + aoff[0]);
    f16x8 a1 = *(const f16x8*)(rd + aoff[1]);
    f16x8 a2 = *(const f16x8*)(rd + aoff[2]);
    f16x8 a3 = *(const f16x8*)(rd + aoff[3]);
    f16x8 bo0 = *(const f16x8*)(Aw + 3 * 16384 + ((0 * 8 + w) * 64 + lane) * 8);
    f16x8 bo1 = *(const f16x8*)(Aw + 3 * 16384 + ((1 * 8 + w) * 64 + lane) * 8);
    f16x8 bo2 = *(const f16x8*)(Aw + 3 * 16384 + ((2 * 8 + w) * 64 + lane) * 8);
    f16x8 bo3 = *(const f16x8*)(Aw + 3 * 16384 + ((3 * 8 + w) * 64 + lane) * 8);
    f32x4 zf  = MFMA16(wr[0][0], a0, u[0]);
    f32x4 zi1 = MFMA16(wr[1][0], a0, u[1]);
    f32x4 zi2 = MFMA16(wr[2][0], a0, u[2]);
    f32x4 zo  = MFMA16(bo0,      a0, u[3]);
    zf  = MFMA16(wr[0][1], a1, zf);
    zi1 = MFMA16(wr[1][1], a1, zi1);
    zi2 = MFMA16(wr[2][1], a1, zi2);
    zo  = MFMA16(bo1,      a1, zo);
    zf  = MFMA16(wr[0][2], a2, zf);
    zi1 = MFMA16(wr[1][2], a2, zi1);
    zi2 = MFMA16(wr[2][2], a2, zi2);
    zo  = MFMA16(bo2,      a2, zo);
    zf  = MFMA16(wr[0][3], a3, zf);
    zi1 = MFMA16(wr[1][3], a3, zi1);
    zi2 = MFMA16(wr[2][3], a3, zi2);
    zo  = MFMA16(bo3,      a3, zo);
    f16x4 hv;
#pragma unroll
    for (int i = 0; i < 4; ++i) {
      float fg = sig2(zf[i]);
      float ig = sig2(zi1[i]);
      float gg = tanh2(zi2[i]);
      float cn = fmaf(cr[i], fg, ig * gg);
      cr[i] = cn;
      float ov = sig2(zo[i]) * tanh2(cn * LOG2E2);  // cn unscaled
      hv[i] = (_Float16)ov;
    }
    // xs region is long dead (last read before step 0); o is disjoint from cF
    *(f16x4*)&uS.ep.o[woff] = hv;
    __syncthreads();
  }

  // -------- epilogue: e = exp2(o @ Wc_scaled + bc*log2e), softmax ---------
  // |s| small (o in (-1,1), Wc ~ N(0,1/sqrt(128))) => max-free softmax.
  {
    f32x4 sacc;
#pragma unroll
    for (int i = 0; i < 4; ++i) sacc[i] = 0.f;
#pragma unroll
    for (int ks = 0; ks < 4; ++ks) {
      f16x8 a = *(const f16x8*)&uS.ep.o[aoff[ks]];
      f16x8 b = *(const f16x8*)(Wcw + ((ks * 8 + w) * 64 + lane) * 8);
      sacc = MFMA16(b, a, sacc);
    }
    f32x4 bcv = *(const f32x4*)&bc[col0];
    f32x4 ev;
#pragma unroll
    for (int i = 0; i < 4; ++i)
      ev[i] = __builtin_amdgcn_exp2f(fmaf(bcv[i], LOG2E, sacc[i]));
    *(f32x4*)&uS.ep.e[n16][col0] = ev;     // single b128 store (e is padded f32)
    __syncthreads();

    // wave w reduces rows w*2, w*2+1; lane covers cols {lane, lane+64}
#pragma unroll
    for (int rr = 0; rr < 2; ++rr) {
      int r = w * 2 + rr;
      float e0 = uS.ep.e[r][lane];
      float e1 = uS.ep.e[r][lane + 64];
      float sm = e0 + e1;
#pragma unroll
      for (int off = 32; off; off >>= 1) sm += __shfl_xor(sm, off, 64);
      float inv = __builtin_amdgcn_rcpf(sm);
      size_t base = (size_t)(r0 + r) * 128;
      out[base + lane]      = e0 * inv;
      out[base + lane + 64] = e1 * inv;
    }

    // final c (output 1) at offset ROWS*128 — float4 store per lane
    *(f32x4*)&out[(size_t)ROWS * 128 + (size_t)(r0 + n16) * 128 + col0] = cr;
  }
}

extern "C" void kernel_launch(void* const* d_in, const int* in_sizes, int n_in,
                              void* d_out, int out_size, void* d_ws, size_t ws_size,
                              hipStream_t stream) {
  const float* x   = (const float*)d_in[0];
  const float* Wf  = (const float*)d_in[1];
  const float* bf_ = (const float*)d_in[2];
  const float* Wi1 = (const float*)d_in[3];
  const float* bi1 = (const float*)d_in[4];
  const float* Wi2 = (const float*)d_in[5];
  const float* bi2 = (const float*)d_in[6];
  const float* Wo  = (const float*)d_in[7];
  const float* bo  = (const float*)d_in[8];
  const float* Wc  = (const float*)d_in[9];
  const float* bc  = (const float*)d_in[10];
  unsigned short* ws = (unsigned short*)d_ws;
  float* out = (float*)d_out;

  hipLaunchKernelGGL(prep_kernel, dim3((NT8 + 255) / 256), dim3(256), 0, stream,
                     Wf, Wi1, Wi2, Wo, Wc, ws);
  hipLaunchKernelGGL(lstm_kernel, dim3(ROWS / RPB), dim3(512), 0, stream,
                     x, bf_, bi1, bi2, bo, bc, ws, out);
}

// Round 10
// 164.228 us; speedup vs baseline: 1.8610x; 1.0056x over previous
//
#include <hip/hip_runtime.h>
#include <stdint.h>

// Problem constants
#define ROWS  16384   // B*T = 512*32
#define CELL  128
#define INF   512
#define RPB   32      // rows per block = 2 x 16-row groups
#define NSTEP 32

typedef _Float16 f16x8 __attribute__((ext_vector_type(8)));
typedef _Float16 f16x4 __attribute__((ext_vector_type(4)));
typedef float    f32x4 __attribute__((ext_vector_type(4)));

#define MFMA16(a, b, c) __builtin_amdgcn_mfma_f32_16x16x32_f16((a), (b), (c), 0, 0, 0)

// ws layout (f16 elems), all in 16x16x32 fragment order:
//   A_sw[g]  at g*16384          (g=0..3: Wf,Wi1,Wi2,Wo rows 0..127, cell part)
//   Xw_sw[g] at 65536 + g*65536  (rows 128..639, x part)
//   Wc_sw    at 327680
// frag addr: ((ks*8 + nb)*64 + lane)*8 + j  <->
//   W[ks*32 + ((lane>>4)<<3) + j][nb*16 + (lane&15)]
// Weights PRE-SCALED: Wf,Wi1,Wo by log2(e); Wi2 by 2*log2(e); Wc by log2(e).
#define AOFF  0
#define XOFF  65536
#define WCOFF 327680
#define WSTOT 344064
#define NT8   (WSTOT / 8)   // 43008 threads, one f16x8 store each

#define LOG2E  1.44269504f
#define LOG2E2 2.88539008f

__device__ __forceinline__ float sig2(float z) {
  return __builtin_amdgcn_rcpf(1.f + __builtin_amdgcn_exp2f(-z));
}
__device__ __forceinline__ float tanh2(float z) {
  return 1.f - 2.f * __builtin_amdgcn_rcpf(__builtin_amdgcn_exp2f(z) + 1.f);
}

// prep v2: COALESCED (verified R9). Thread t emits ws[t*8..t*8+7].
__global__ __launch_bounds__(256) void prep_kernel(
    const float* __restrict__ Wf, const float* __restrict__ Wi1,
    const float* __restrict__ Wi2, const float* __restrict__ Wo,
    const float* __restrict__ Wc, unsigned short* __restrict__ ws) {
  int t = blockIdx.x * blockDim.x + threadIdx.x;
  if (t >= NT8) return;
  const float* Wg[4] = {Wf, Wi1, Wi2, Wo};
  const float scl[4] = {LOG2E, LOG2E, LOG2E2, LOG2E};
  const int lane = t & 63;
  const int tile = t >> 6;             // global 512-f16 tile, 0..671

  const float* src;
  float sc;
  int ks, nb;
  if (tile < 128) {                    // A region: recurrent (cell) part
    int g = tile >> 5, tA = tile & 31;
    ks = tA >> 3; nb = tA & 7;
    sc = scl[g];
    src = Wg[g];
  } else if (tile < 640) {             // X region: x part, W rows 128..639
    int rel = tile - 128;
    int g = rel >> 7, tX = rel & 127;
    ks = tX >> 3; nb = tX & 7;
    sc = scl[g];
    src = Wg[g] + 128 * CELL;
  } else {                             // Wc region
    int rel = tile - 640;
    ks = rel >> 3; nb = rel & 7;
    sc = LOG2E;
    src = Wc;
  }
  const int k0 = ks * 32 + ((lane >> 4) << 3);
  const int n  = nb * 16 + (lane & 15);
  const float* p = src + (size_t)k0 * CELL + n;
  f16x8 hv;
#pragma unroll
  for (int j = 0; j < 8; ++j) hv[j] = (_Float16)(p[j * CELL] * sc);
  *(f16x8*)&ws[(size_t)t * 8] = hv;
}

// 32 rows/block, 8 waves, two 16-row groups per step with ONE barrier.
// (R5 structure, verified correct, minus its register penalty.)
// Fused gate math: ig*gg = (E-1)*rcp((1+A)(E+1)) — one shared rcp,
// 5 trans/element instead of 6; fminf(zi2,126) guards E=inf (product
// overflow then gives igg=0, which matches the true limit).
__global__ __launch_bounds__(512, 4) void lstm_kernel(
    const float* __restrict__ x,
    const float* __restrict__ bf_, const float* __restrict__ bi1,
    const float* __restrict__ bi2, const float* __restrict__ bo,
    const float* __restrict__ bc,
    const unsigned short* __restrict__ ws, float* __restrict__ out) {

  __shared__ _Float16 cF[2][32 * 128];       // 16384 B, double-buffered c (swz)
  __shared__ union {
    _Float16 xs[32 * 512];                   // 32768 B, x staging (swz)
    struct {
      float    ue[32][132];                  // 16896 B: u_o / softmax e
      _Float16 o[32 * 128];                  // 8192 B, o activations (swz)
    } ep;                                    // 25088 B
  } uS;                                      // total LDS: 49152 B

  const int tid  = threadIdx.x;
  const int lane = tid & 63;
  const int w    = tid >> 6;     // wave 0..7
  const int n16  = lane & 15;
  const int g4   = lane >> 4;
  const int sxor = n16 & 7;
  const int col0 = w * 16 + g4 * 4;
  const int r0   = blockIdx.x * RPB;

  const _Float16* Aw  = (const _Float16*)ws + AOFF;
  const _Float16* Xw  = (const _Float16*)ws + XOFF;
  const _Float16* Wcw = (const _Float16*)ws + WCOFF;

  int aoff[4];
#pragma unroll
  for (int ks = 0; ks < 4; ++ks)
    aoff[ks] = n16 * 128 + (((4 * ks + g4) ^ sxor) << 3);
  const int woff = n16 * 128 + (((2 * w + (g4 >> 1)) ^ sxor) << 3) + (g4 & 1) * 4;

  // ---------------- stage x (32 rows x 512 f32 -> f16, swizzled) ----------
  {
    const float* xb = x + (size_t)r0 * INF;
#pragma unroll
    for (int i = 0; i < 8; ++i) {
      int flat = tid + i * 512;            // 4096 = 32 rows * 128 float4
      int row = flat >> 7, c4 = flat & 127;
      const float4 v = ((const float4*)(xb + (size_t)row * INF))[c4];
      f16x4 h = {(_Float16)v.x, (_Float16)v.y, (_Float16)v.z, (_Float16)v.w};
      int idx = row * 512 + (((c4 >> 1) ^ (row & 7)) << 3) + (c4 & 1) * 4;
      *(f16x4*)&uS.xs[idx] = h;
    }
  }
  __syncthreads();

  // ---------------- u[h][g] = x @ Wg[128:,:] + b --------------------------
  f32x4 u[2][4];
#pragma unroll
  for (int h = 0; h < 2; ++h)
#pragma unroll
    for (int g = 0; g < 4; ++g)
#pragma unroll
      for (int i = 0; i < 4; ++i) u[h][g][i] = 0.f;

#pragma unroll 2
  for (int ks = 0; ks < 16; ++ks) {
    f16x8 b0 = *(const f16x8*)(Xw + 0 * 65536 + ((ks * 8 + w) * 64 + lane) * 8);
    f16x8 b1 = *(const f16x8*)(Xw + 1 * 65536 + ((ks * 8 + w) * 64 + lane) * 8);
    f16x8 b2 = *(const f16x8*)(Xw + 2 * 65536 + ((ks * 8 + w) * 64 + lane) * 8);
    f16x8 b3 = *(const f16x8*)(Xw + 3 * 65536 + ((ks * 8 + w) * 64 + lane) * 8);
#pragma unroll
    for (int h = 0; h < 2; ++h) {
      f16x8 a = *(const f16x8*)&uS.xs[(h * 16 + n16) * 512 +
                                      (((4 * ks + g4) ^ sxor) << 3)];
      u[h][0] = MFMA16(b0, a, u[h][0]);
      u[h][1] = MFMA16(b1, a, u[h][1]);
      u[h][2] = MFMA16(b2, a, u[h][2]);
      u[h][3] = MFMA16(b3, a, u[h][3]);
    }
  }
  {
    f32x4 b0 = *(const f32x4*)&bf_[col0];
    f32x4 b1 = *(const f32x4*)&bi1[col0];
    f32x4 b2 = *(const f32x4*)&bi2[col0];
    f32x4 b3 = *(const f32x4*)&bo[col0];
#pragma unroll
    for (int h = 0; h < 2; ++h)
#pragma unroll
      for (int i = 0; i < 4; ++i) {
        u[h][0][i] = fmaf(b0[i], LOG2E,  u[h][0][i]);
        u[h][1][i] = fmaf(b1[i], LOG2E,  u[h][1][i]);
        u[h][2][i] = fmaf(b2[i], LOG2E2, u[h][2][i]);
        u[h][3][i] = fmaf(b3[i], LOG2E,  u[h][3][i]);
      }
  }
  __syncthreads();   // all xs reads done; ue region becomes safe to write

  // park o-gate preactivation in LDS (frees 8 VGPR for the hot loop)
  *(f32x4*)&uS.ep.ue[n16][col0]      = u[0][3];
  *(f32x4*)&uS.ep.ue[16 + n16][col0] = u[1][3];

  // ---------------- recurrent-gate weights -> registers -------------------
  f16x8 wr[3][4];   // 48 VGPRs
#pragma unroll
  for (int g = 0; g < 3; ++g)
#pragma unroll
    for (int ks = 0; ks < 4; ++ks)
      wr[g][ks] = *(const f16x8*)(Aw + g * 16384 + ((ks * 8 + w) * 64 + lane) * 8);

  // fused cell update: cn = cr*sig(zf) + sig(zi1)*tanh(zi2), 5 trans
#define GATES(ZF, ZI, ZG, CR, BUF, OFS) { \
  f16x4 hv; \
  _Pragma("unroll") \
  for (int i = 0; i < 4; ++i) { \
    float F = __builtin_amdgcn_exp2f(-(ZF)[i]); \
    float A = __builtin_amdgcn_exp2f(-(ZI)[i]); \
    float E = __builtin_amdgcn_exp2f(fminf((ZG)[i], 126.f)); \
    float fg  = __builtin_amdgcn_rcpf(1.f + F); \
    float igg = (E - 1.f) * __builtin_amdgcn_rcpf((1.f + A) * (E + 1.f)); \
    float cn = fmaf((CR)[i], fg, igg); \
    (CR)[i] = cn; \
    hv[i] = (_Float16)cn; \
  } \
  *(f16x4*)&(BUF)[(OFS) + woff] = hv; }

  // ---------------- step 0: c_prev = 0 ------------------------------------
  f32x4 cr0, cr1;
#pragma unroll
  for (int i = 0; i < 4; ++i) { cr0[i] = 0.f; cr1[i] = 0.f; }
  GATES(u[0][0], u[0][1], u[0][2], cr0, cF[0], 0)
  GATES(u[1][0], u[1][1], u[1][2], cr1, cF[0], 2048)
  __syncthreads();

  // ---------------- recurrence: steps 1..30, 1 barrier/step ---------------
#pragma unroll 1
  for (int t = 1; t < NSTEP - 1; ++t) {
    const _Float16* rd = cF[(t + 1) & 1];
    _Float16*       wp = cF[t & 1];
    // group 0
    f16x8 a0 = *(const f16x8*)(rd + aoff[0]);
    f16x8 a1 = *(const f16x8*)(rd + aoff[1]);
    f16x8 a2 = *(const f16x8*)(rd + aoff[2]);
    f16x8 a3 = *(const f16x8*)(rd + aoff[3]);
    f32x4 zf  = MFMA16(wr[0][0], a0, u[0][0]);
    f32x4 zi1 = MFMA16(wr[1][0], a0, u[0][1]);
    f32x4 zi2 = MFMA16(wr[2][0], a0, u[0][2]);
    zf  = MFMA16(wr[0][1], a1, zf);
    zi1 = MFMA16(wr[1][1], a1, zi1);
    zi2 = MFMA16(wr[2][1], a1, zi2);
    zf  = MFMA16(wr[0][2], a2, zf);
    zi1 = MFMA16(wr[1][2], a2, zi1);
    zi2 = MFMA16(wr[2][2], a2, zi2);
    zf  = MFMA16(wr[0][3], a3, zf);
    zi1 = MFMA16(wr[1][3], a3, zi1);
    zi2 = MFMA16(wr[2][3], a3, zi2);
    // group 1 frags issued here; latency hides under group-0 gate math
    f16x8 e0 = *(const f16x8*)(rd + 2048 + aoff[0]);
    f16x8 e1 = *(const f16x8*)(rd + 2048 + aoff[1]);
    f16x8 e2 = *(const f16x8*)(rd + 2048 + aoff[2]);
    f16x8 e3 = *(const f16x8*)(rd + 2048 + aoff[3]);
    GATES(zf, zi1, zi2, cr0, wp, 0)
    zf  = MFMA16(wr[0][0], e0, u[1][0]);
    zi1 = MFMA16(wr[1][0], e0, u[1][1]);
    zi2 = MFMA16(wr[2][0], e0, u[1][2]);
    zf  = MFMA16(wr[0][1], e1, zf);
    zi1 = MFMA16(wr[1][1], e1, zi1);
    zi2 = MFMA16(wr[2][1], e1, zi2);
    zf  = MFMA16(wr[0][2], e2, zf);
    zi1 = MFMA16(wr[1][2], e2, zi1);
    zi2 = MFMA16(wr[2][2], e2, zi2);
    zf  = MFMA16(wr[0][3], e3, zf);
    zi1 = MFMA16(wr[1][3], e3, zi1);
    zi2 = MFMA16(wr[2][3], e3, zi2);
    GATES(zf, zi1, zi2, cr1, wp, 2048)
    __syncthreads();
  }

  // ---------------- final step (t=31): + o-gate ---------------------------
  {
    const _Float16* rd = cF[0];            // written at t=30
    f16x8 bo0 = *(const f16x8*)(Aw + 3 * 16384 + ((0 * 8 + w) * 64 + lane) * 8);
    f16x8 bo1 = *(const f16x8*)(Aw + 3 * 16384 + ((1 * 8 + w) * 64 + lane) * 8);
    f16x8 bo2 = *(const f16x8*)(Aw + 3 * 16384 + ((2 * 8 + w) * 64 + lane) * 8);
    f16x8 bo3 = *(const f16x8*)(Aw + 3 * 16384 + ((3 * 8 + w) * 64 + lane) * 8);
#pragma unroll
    for (int h = 0; h < 2; ++h) {
      const int hoff = h * 2048;
      f16x8 a0 = *(const f16x8*)(rd + hoff + aoff[0]);
      f16x8 a1 = *(const f16x8*)(rd + hoff + aoff[1]);
      f16x8 a2 = *(const f16x8*)(rd + hoff + aoff[2]);
      f16x8 a3 = *(const f16x8*)(rd + hoff + aoff[3]);
      f32x4 zos = *(const f32x4*)&uS.ep.ue[h * 16 + n16][col0];
      f32x4 zf  = MFMA16(wr[0][0], a0, u[h][0]);
      f32x4 zi1 = MFMA16(wr[1][0], a0, u[h][1]);
      f32x4 zi2 = MFMA16(wr[2][0], a0, u[h][2]);
      f32x4 zo  = MFMA16(bo0,      a0, zos);
      zf  = MFMA16(wr[0][1], a1, zf);
      zi1 = MFMA16(wr[1][1], a1, zi1);
      zi2 = MFMA16(wr[2][1], a1, zi2);
      zo  = MFMA16(bo1,      a1, zo);
      zf  = MFMA16(wr[0][2], a2, zf);
      zi1 = MFMA16(wr[1][2], a2, zi1);
      zi2 = MFMA16(wr[2][2], a2, zi2);
      zo  = MFMA16(bo2,      a2, zo);
      zf  = MFMA16(wr[0][3], a3, zf);
      zi1 = MFMA16(wr[1][3], a3, zi1);
      zi2 = MFMA16(wr[2][3], a3, zi2);
      zo  = MFMA16(bo3,      a3, zo);
      f16x4 hv;
      f32x4& cr = h ? cr1 : cr0;
#pragma unroll
      for (int i = 0; i < 4; ++i) {
        float F = __builtin_amdgcn_exp2f(-zf[i]);
        float A = __builtin_amdgcn_exp2f(-zi1[i]);
        float E = __builtin_amdgcn_exp2f(fminf(zi2[i], 126.f));
        float fg  = __builtin_amdgcn_rcpf(1.f + F);
        float igg = (E - 1.f) * __builtin_amdgcn_rcpf((1.f + A) * (E + 1.f));
        float cn = fmaf(cr[i], fg, igg);
        cr[i] = cn;
        float ov = sig2(zo[i]) * tanh2(cn * LOG2E2);  // cn unscaled
        hv[i] = (_Float16)ov;
      }
      *(f16x4*)&uS.ep.o[hoff + woff] = hv;
    }
  }
  __syncthreads();

  // -------- epilogue: e = exp2(o @ Wc_scaled + bc*log2e), softmax ---------
  {
    f32x4 s0, s1;
#pragma unroll
    for (int i = 0; i < 4; ++i) { s0[i] = 0.f; s1[i] = 0.f; }
#pragma unroll
    for (int ks = 0; ks < 4; ++ks) {
      f16x8 bW = *(const f16x8*)(Wcw + ((ks * 8 + w) * 64 + lane) * 8);
      f16x8 oa = *(const f16x8*)&uS.ep.o[aoff[ks]];
      f16x8 ob = *(const f16x8*)&uS.ep.o[2048 + aoff[ks]];
      s0 = MFMA16(bW, oa, s0);
      s1 = MFMA16(bW, ob, s1);
    }
    f32x4 bcv = *(const f32x4*)&bc[col0];
    f32x4 ev0, ev1;
#pragma unroll
    for (int i = 0; i < 4; ++i) {
      ev0[i] = __builtin_amdgcn_exp2f(fmaf(bcv[i], LOG2E, s0[i]));
      ev1[i] = __builtin_amdgcn_exp2f(fmaf(bcv[i], LOG2E, s1[i]));
    }
    *(f32x4*)&uS.ep.ue[n16][col0]      = ev0;
    *(f32x4*)&uS.ep.ue[16 + n16][col0] = ev1;
    __syncthreads();

    // wave w reduces rows w*4 .. w*4+3; lane covers cols {lane, lane+64}
#pragma unroll
    for (int rr = 0; rr < 4; ++rr) {
      int r = w * 4 + rr;
      float e0 = uS.ep.ue[r][lane];
      float e1 = uS.ep.ue[r][lane + 64];
      float sm = e0 + e1;
#pragma unroll
      for (int off = 32; off; off >>= 1) sm += __shfl_xor(sm, off, 64);
      float inv = __builtin_amdgcn_rcpf(sm);
      size_t base = (size_t)(r0 + r) * 128;
      out[base + lane]      = e0 * inv;
      out[base + lane + 64] = e1 * inv;
    }

    // final c (output 1) at offset ROWS*128 — float4 store per lane
    *(f32x4*)&out[(size_t)ROWS * 128 + (size_t)(r0 + n16) * 128 + col0] = cr0;
    *(f32x4*)&out[(size_t)ROWS * 128 + (size_t)(r0 + 16 + n16) * 128 + col0] = cr1;
  }
}

extern "C" void kernel_launch(void* const* d_in, const int* in_sizes, int n_in,
                              void* d_out, int out_size, void* d_ws, size_t ws_size,
                              hipStream_t stream) {
  const float* x   = (const float*)d_in[0];
  const float* Wf  = (const float*)d_in[1];
  const float* bf_ = (const float*)d_in[2];
  const float* Wi1 = (const float*)d_in[3];
  const float* bi1 = (const float*)d_in[4];
  const float* Wi2 = (const float*)d_in[5];
  const float* bi2 = (const float*)d_in[6];
  const float* Wo  = (const float*)d_in[7];
  const float* bo  = (const float*)d_in[8];
  const float* Wc  = (const float*)d_in[9];
  const float* bc  = (const float*)d_in[10];
  unsigned short* ws = (unsigned short*)d_ws;
  float* out = (float*)d_out;

  hipLaunchKernelGGL(prep_kernel, dim3((NT8 + 255) / 256), dim3(256), 0, stream,
                     Wf, Wi1, Wi2, Wo, Wc, ws);
  hipLaunchKernelGGL(lstm_kernel, dim3(ROWS / RPB), dim3(512), 0, stream,
                     x, bf_, bi1, bi2, bo, bc, ws, out);
}